// Round 1
// baseline (1003.199 us; speedup 1.0000x reference)
//
#include <hip/hip_runtime.h>
#include <hip/hip_bf16.h>

// Problem constants (match reference setup_inputs)
constexpr int T = 8;
constexpr int R = 200000;
constexpr int D = 128;
constexpr int B = 2048;
constexpr int NUM_BAGS = T * B;  // 16384

// One 64-lane wave per bag. Two half-waves each process one lookup per
// iteration; lane s in a half-wave loads int4 (16B) covering dims [4s, 4s+4).
// A full row (128 x int32 = 512B) is one coalesced 32-lane x 16B transaction.
__global__ __launch_bounds__(256)
void qembag_kernel(const int* __restrict__ indices,
                   const int* __restrict__ offsets,
                   const int* __restrict__ qweights,
                   const float* __restrict__ scale_shift,
                   float* __restrict__ out) {
    const int wave_id = (int)((blockIdx.x * blockDim.x + threadIdx.x) >> 6);
    if (wave_id >= NUM_BAGS) return;
    const int lane = (int)(threadIdx.x & 63);
    const int half = lane >> 5;   // which lookup of the pair
    const int sub  = lane & 31;   // 16B chunk within the row

    const int bag   = wave_id;
    const int t     = bag >> 11;      // bag / B   (B = 2048)
    const int batch = bag & (B - 1);  // bag % B

    const int start = offsets[bag];
    const int end   = offsets[bag + 1];

    float acc0 = 0.f, acc1 = 0.f, acc2 = 0.f, acc3 = 0.f;

    const long tbase = (long)t * R;

    for (int j = start + half; j < end; j += 2) {
        const int idx = indices[j];                 // broadcast within half-wave
        const long row = tbase + idx;
        const int4 q = ((const int4*)(qweights + row * (long)D))[sub];
        const float2 ss = ((const float2*)scale_shift)[row];
        const float scale = ss.x, shift = ss.y;
        acc0 = fmaf((float)q.x, scale, acc0 + shift);
        acc1 = fmaf((float)q.y, scale, acc1 + shift);
        acc2 = fmaf((float)q.z, scale, acc2 + shift);
        acc3 = fmaf((float)q.w, scale, acc3 + shift);
    }

    // Fold the two half-wave partial sums: lane s += lane s+32
    acc0 += __shfl_down(acc0, 32);
    acc1 += __shfl_down(acc1, 32);
    acc2 += __shfl_down(acc2, 32);
    acc3 += __shfl_down(acc3, 32);

    if (half == 0) {
        float4 v = make_float4(acc0, acc1, acc2, acc3);
        ((float4*)(out + (long)batch * (T * D) + t * D))[sub] = v;
    }
}

extern "C" void kernel_launch(void* const* d_in, const int* in_sizes, int n_in,
                              void* d_out, int out_size, void* d_ws, size_t ws_size,
                              hipStream_t stream) {
    const int*   indices     = (const int*)d_in[0];
    const int*   offsets     = (const int*)d_in[1];
    const int*   qweights    = (const int*)d_in[2];
    const float* scale_shift = (const float*)d_in[3];
    float*       out         = (float*)d_out;

    // 4 waves per 256-thread block, one wave per bag
    const int blocks = NUM_BAGS / 4;  // 4096
    qembag_kernel<<<blocks, 256, 0, stream>>>(indices, offsets, qweights,
                                              scale_shift, out);
}

// Round 2
// 931.688 us; speedup vs baseline: 1.0768x; 1.0768x over previous
//
#include <hip/hip_runtime.h>
#include <hip/hip_bf16.h>

// Problem constants (match reference setup_inputs)
constexpr int T = 8;
constexpr int R = 200000;
constexpr int D = 128;
constexpr int B = 2048;
constexpr int NUM_BAGS = T * B;  // 16384

// One 64-lane wave per bag, two half-waves each own alternating lookups.
// Key change vs R1: unroll-by-8 per half — preload 8 indices, then issue all
// 8 row gathers (each a coalesced 32-lane x 16B = 512B read) + 8 scale/shift
// gathers BEFORE accumulating. 16 rows in flight per wave instead of 2.
__global__ __launch_bounds__(256)
void qembag_kernel(const int* __restrict__ indices,
                   const int* __restrict__ offsets,
                   const int* __restrict__ qweights,
                   const float* __restrict__ scale_shift,
                   float* __restrict__ out) {
    const int wave_id = (int)((blockIdx.x * blockDim.x + threadIdx.x) >> 6);
    if (wave_id >= NUM_BAGS) return;
    const int lane = (int)(threadIdx.x & 63);
    const int half = lane >> 5;   // which lookup of an interleaved pair
    const int sub  = lane & 31;   // 16B chunk within the 512B row

    const int bag   = wave_id;
    const int t     = bag >> 11;      // bag / B   (B = 2048)
    const int batch = bag & (B - 1);  // bag % B

    const int start = offsets[bag];
    const int end   = offsets[bag + 1];
    const int len   = end - start;
    const int C     = len >> 4;       // full chunks of 16 lookups (8 per half)

    float acc0 = 0.f, acc1 = 0.f, acc2 = 0.f, acc3 = 0.f;

    const long tbase = (long)t * R;
    const int4*   qw4 = (const int4*)qweights;      // row r -> qw4[r*32 + sub]
    const float2* ss2 = (const float2*)scale_shift; // row r -> ss2[r]

    for (int c = 0; c < C; ++c) {
        const int base = start + (c << 4) + half;

        // 1) preload 8 indices (independent loads, mostly L1/L2 hits)
        int idx[8];
#pragma unroll
        for (int k = 0; k < 8; ++k) idx[k] = indices[base + 2 * k];

        // 2) issue all 16 gathers (8 rows + 8 scale/shift) back-to-back
        int4   q[8];
        float2 s[8];
#pragma unroll
        for (int k = 0; k < 8; ++k) {
            const long r = tbase + idx[k];
            q[k] = qw4[r * 32 + sub];
            s[k] = ss2[r];
        }

        // 3) accumulate
#pragma unroll
        for (int k = 0; k < 8; ++k) {
            const float sc = s[k].x, sh = s[k].y;
            acc0 = fmaf((float)q[k].x, sc, acc0 + sh);
            acc1 = fmaf((float)q[k].y, sc, acc1 + sh);
            acc2 = fmaf((float)q[k].z, sc, acc2 + sh);
            acc3 = fmaf((float)q[k].w, sc, acc3 + sh);
        }
    }

    // remainder (< 16 lookups), interleaved between halves as before
    for (int j = start + (C << 4) + half; j < end; j += 2) {
        const int idx = indices[j];
        const long r = tbase + idx;
        const int4 q = qw4[r * 32 + sub];
        const float2 ss = ss2[r];
        acc0 = fmaf((float)q.x, ss.x, acc0 + ss.y);
        acc1 = fmaf((float)q.y, ss.x, acc1 + ss.y);
        acc2 = fmaf((float)q.z, ss.x, acc2 + ss.y);
        acc3 = fmaf((float)q.w, ss.x, acc3 + ss.y);
    }

    // Fold the two half-wave partial sums: lane s += lane s+32
    acc0 += __shfl_down(acc0, 32);
    acc1 += __shfl_down(acc1, 32);
    acc2 += __shfl_down(acc2, 32);
    acc3 += __shfl_down(acc3, 32);

    if (half == 0) {
        float4 v = make_float4(acc0, acc1, acc2, acc3);
        ((float4*)(out + (long)batch * (T * D) + t * D))[sub] = v;
    }
}

extern "C" void kernel_launch(void* const* d_in, const int* in_sizes, int n_in,
                              void* d_out, int out_size, void* d_ws, size_t ws_size,
                              hipStream_t stream) {
    const int*   indices     = (const int*)d_in[0];
    const int*   offsets     = (const int*)d_in[1];
    const int*   qweights    = (const int*)d_in[2];
    const float* scale_shift = (const float*)d_in[3];
    float*       out         = (float*)d_out;

    // 4 waves per 256-thread block, one wave per bag
    const int blocks = NUM_BAGS / 4;  // 4096
    qembag_kernel<<<blocks, 256, 0, stream>>>(indices, offsets, qweights,
                                              scale_shift, out);
}